// Round 3
// baseline (35602.744 us; speedup 1.0000x reference)
//
#include <hip/hip_runtime.h>
#include <hip/hip_fp16.h>
#include <stdint.h>

// TKANCell B=64,T=2048,D=128,U=128,NS=3. fp32 in/out (confirmed R2:
// WRITE_SIZE=64MiB). 64 independent chains (tf.reshape routes sub-row
// r=3b'+j to batch b' only). R2 was L2-latency bound: 1 wave/SIMD, ILP~4,
// 17.3us/step. R3: 1024-thr WGs (4 waves/SIMD), K=32-chunk subtasks with
// full-unroll 32-load dots + LDS partial reduce; weights converted to fp16
// in d_ws (half the 1.16MB/step stream; |w|<0.3 so fp16 rel err 5e-4).

#define TT 2048
#define BB 64

__device__ __forceinline__ float sigf(float x) { return 1.0f / (1.0f + __expf(-x)); }
__device__ __forceinline__ float tanh_(float x) { return 2.0f / (1.0f + __expf(-2.0f * x)) - 1.0f; }

template <bool HALF>
__device__ __forceinline__ float2 ldpair(const void* base, int idx) {
    if (HALF) {
        __half2 w = ((const __half2*)base)[idx];
        return __half22float2(w);
    }
    return ((const float2*)base)[idx];
}

// rE = sum_{k<32} W[row0+k][2q]*v[k] ; rO = same for col 2q+1.
// base indexed in element-PAIRS, row stride `stride` pairs.
template <bool HALF>
__device__ __forceinline__ void dot32(const void* base, int idx0, int stride,
                                      const float* __restrict__ v,
                                      float& rE, float& rO) {
    float e0 = 0, e1 = 0, e2 = 0, e3 = 0, o0 = 0, o1 = 0, o2 = 0, o3 = 0;
#pragma unroll
    for (int k = 0; k < 32; k += 4) {
        float2 f0 = ldpair<HALF>(base, idx0 + k * stride);
        float2 f1 = ldpair<HALF>(base, idx0 + (k + 1) * stride);
        float2 f2 = ldpair<HALF>(base, idx0 + (k + 2) * stride);
        float2 f3 = ldpair<HALF>(base, idx0 + (k + 3) * stride);
        e0 += f0.x * v[k];     o0 += f0.y * v[k];
        e1 += f1.x * v[k + 1]; o1 += f1.y * v[k + 1];
        e2 += f2.x * v[k + 2]; o2 += f2.y * v[k + 2];
        e3 += f3.x * v[k + 3]; o3 += f3.y * v[k + 3];
    }
    rE = (e0 + e1) + (e2 + e3);
    rO = (o0 + o1) + (o2 + o3);
}

// Convert the 6 weight matrices (each 49152 fp32) to fp16 in ws.
__global__ __launch_bounds__(1024) void convert_w(
    const float* __restrict__ Wk, const float* __restrict__ Wr,
    const float* __restrict__ Wx, const float* __restrict__ Wh,
    const float* __restrict__ Dw, const float* __restrict__ Aw,
    __half* __restrict__ dst) {
    int gidx = blockIdx.x * 1024 + threadIdx.x;  // 0..294911
    int seg = gidx / 49152, idx = gidx % 49152;
    const float* src = (seg == 0) ? Wk : (seg == 1) ? Wr : (seg == 2) ? Wx
                      : (seg == 3) ? Wh : (seg == 4) ? Dw : Aw;
    dst[gidx] = __float2half(src[idx]);
}

// Weight pair-buffer geometry (in PAIRS):
//  wk,wr: rows 128, stride 192 (384 cols)
//  wx,wh,dw: per-n blocks of 128x64 pairs (8192), stride 64
//  aw: rows 384, stride 64
template <bool HALF>
__global__ __launch_bounds__(1024) void tkan_rec(
    const float* __restrict__ xg,   // (B,T,D) fp32
    const float* __restrict__ bias, // (384)
    const float* __restrict__ stk,  // (3,256) rh|rx
    const float* __restrict__ Db,   // (3,128)
    const float* __restrict__ Ab,   // (128)
    const void* __restrict__ wk, const void* __restrict__ wr,
    const void* __restrict__ wx, const void* __restrict__ wh,
    const void* __restrict__ dw, const void* __restrict__ aw,
    float* __restrict__ outp)       // (B,T,U) fp32
{
    const int bp = blockIdx.x;
    const int tid = threadIdx.x;

    __shared__ float part[6912];           // [pt][kc(8)][2] stride 18 / p3: [pu][kc(12)][2] stride 25
    __shared__ float g[384], pS[384];
    __shared__ float hS[128], cS[128], tcS[128];
    __shared__ float sS[3][128], aS[3][128];
    __shared__ float xb[128], xr[3][128];

    // ---- init: h,c,s zero; load x(t=0)
    if (tid < 128) { hS[tid] = 0.f; cS[tid] = 0.f; }
    else if (tid < 512) { int q = tid - 128; (&sS[0][0])[q] = 0.f; }
    else if (tid < 640) {
        int l = tid - 512, v_ = l >> 5, fe = l & 31;
        int bsrc = (v_ == 0) ? bp : ((3 * bp + (v_ - 1)) & 63);
        const float4* px = (const float4*)(xg + ((size_t)bsrc * TT) * 128);
        float4 w = px[fe];
        float* dst = (v_ == 0) ? xb : xr[v_ - 1];
        dst[fe * 4] = w.x; dst[fe * 4 + 1] = w.y;
        dst[fe * 4 + 2] = w.z; dst[fe * 4 + 3] = w.w;
    }
    __syncthreads();

    for (int t = 0; t < TT; ++t) {
        // ---- Phase 1: 384 pair-cols (192 gates K=256, 192 agg K=256), 8 K-chunks
#pragma unroll
        for (int r = 0; r < 3; ++r) {
            int st = tid + (r << 10);        // 0..3071
            int pt = st % 384;
            int kc = st / 384;               // 0..7
            const void* base; int idx0, stride; const float* v;
            if (pt < 192) {
                stride = 192;
                if (kc < 4) { base = wk; idx0 = (kc * 32) * 192 + pt; v = xb + kc * 32; }
                else        { base = wr; idx0 = ((kc - 4) * 32) * 192 + pt; v = hS + (kc - 4) * 32; }
            } else {
                int q = pt - 192, j = q >> 6, pi = q & 63;
                int nj = (3 * bp + j) >> 6;
                stride = 64;
                if (kc < 4) { base = wx; idx0 = nj * 8192 + (kc * 32) * 64 + pi; v = xr[j] + kc * 32; }
                else        { base = wh; idx0 = nj * 8192 + ((kc - 4) * 32) * 64 + pi; v = sS[j] + (kc - 4) * 32; }
            }
            float aE, aO;
            dot32<HALF>(base, idx0, stride, v, aE, aO);
            part[pt * 18 + kc * 2] = aE;
            part[pt * 18 + kc * 2 + 1] = aO;
        }
        __syncthreads();

        // ---- Phase 1 reduce
        if (tid < 384) {
            float aE = 0.f, aO = 0.f;
#pragma unroll
            for (int kc = 0; kc < 8; ++kc) {
                aE += part[tid * 18 + kc * 2];
                aO += part[tid * 18 + kc * 2 + 1];
            }
            if (tid < 192) {
                g[2 * tid] = aE + bias[2 * tid];
                g[2 * tid + 1] = aO + bias[2 * tid + 1];
            } else {
                int q = tid - 192, j = q >> 6, pi = q & 63;
                aS[j][2 * pi] = aE;
                aS[j][2 * pi + 1] = aO;
            }
        }
        __syncthreads();

        // ---- Phase 2: Dw (192 pair-cols, K=128 -> 4 chunks) ; c-update
        if (tid < 768) {
            int pt = tid % 192, kc = tid / 192;   // kc 0..3
            int j = pt >> 6, po = pt & 63;
            int nj = (3 * bp + j) >> 6;
            float aE, aO;
            dot32<HALF>(dw, nj * 8192 + (kc * 32) * 64 + po, 64, aS[j] + kc * 32, aE, aO);
            part[pt * 18 + kc * 2] = aE;
            part[pt * 18 + kc * 2 + 1] = aO;
        } else if (tid < 896) {
            int u = tid - 768;
            float gi = sigf(g[u]);
            float gf = sigf(g[128 + u]);
            float gc = sigf(g[256 + u]);
            float cn = gf * cS[u] + gi * tanh_(gc);
            cS[u] = cn;
            tcS[u] = tanh_(cn);
        }
        __syncthreads();

        // ---- Phase 2 reduce -> p = relu(.+Db)
        if (tid < 192) {
            float aE = 0.f, aO = 0.f;
#pragma unroll
            for (int kc = 0; kc < 4; ++kc) {
                aE += part[tid * 18 + kc * 2];
                aO += part[tid * 18 + kc * 2 + 1];
            }
            int j = tid >> 6, po = tid & 63;
            int nj = (3 * bp + j) >> 6;
            pS[2 * tid] = fmaxf(aE + Db[nj * 128 + 2 * po], 0.f);
            pS[2 * tid + 1] = fmaxf(aO + Db[nj * 128 + 2 * po + 1], 0.f);
        }
        __syncthreads();

        // ---- Phase 3: Aw (64 pair-cols, K=384 -> 12 chunks)
        if (tid < 768) {
            int pu = tid % 64, kc = tid / 64;   // kc 0..11
            float aE, aO;
            dot32<HALF>(aw, (kc * 32) * 64 + pu, 64, pS + kc * 32, aE, aO);
            part[pu * 25 + kc * 2] = aE;
            part[pu * 25 + kc * 2 + 1] = aO;
        }
        __syncthreads();

        // ---- finalize: y,o,h,out ; s-update ; prefetch x(t+1)
        if (tid < 128) {
            int pu = tid >> 1, e = tid & 1;
            float y = 0.f;
#pragma unroll
            for (int kc = 0; kc < 12; ++kc) y += part[pu * 25 + kc * 2 + e];
            y += Ab[tid];
            float hn = sigf(y) * tcS[tid];
            hS[tid] = hn;
            outp[((size_t)bp * TT + t) * 128 + tid] = hn;
        } else if (tid < 512) {
            int q = tid - 128;                 // 0..383
            int j = q >> 7, o = q & 127;
            int nj = (3 * bp + j) >> 6;
            sS[j][o] = stk[nj * 256 + o] * pS[q] + stk[nj * 256 + 128 + o] * sS[j][o];
        } else if (tid < 640) {
            int l = tid - 512, v_ = l >> 5, fe = l & 31;
            int tn = (t + 1 < TT) ? (t + 1) : (TT - 1);
            int bsrc = (v_ == 0) ? bp : ((3 * bp + (v_ - 1)) & 63);
            const float4* px = (const float4*)(xg + ((size_t)bsrc * TT + tn) * 128);
            float4 w = px[fe];
            float* dst = (v_ == 0) ? xb : xr[v_ - 1];
            dst[fe * 4] = w.x; dst[fe * 4 + 1] = w.y;
            dst[fe * 4 + 2] = w.z; dst[fe * 4 + 3] = w.w;
        }
        __syncthreads();
    }
}

extern "C" void kernel_launch(void* const* d_in, const int* in_sizes, int n_in,
                              void* d_out, int out_size, void* d_ws, size_t ws_size,
                              hipStream_t stream) {
    const float* x    = (const float*)d_in[0];
    const float* Wk   = (const float*)d_in[1];
    const float* Wr   = (const float*)d_in[2];
    const float* bias = (const float*)d_in[3];
    const float* Wx   = (const float*)d_in[4];
    const float* Wh   = (const float*)d_in[5];
    const float* stk  = (const float*)d_in[6];
    const float* Dw   = (const float*)d_in[7];
    const float* Db   = (const float*)d_in[8];
    const float* Aw   = (const float*)d_in[9];
    const float* Ab   = (const float*)d_in[10];
    float* outp = (float*)d_out;

    const size_t needW = 294912 * sizeof(__half);   // 589824 B
    if (ws_size >= needW) {
        __half* w2 = (__half*)d_ws;
        convert_w<<<dim3(288), dim3(1024), 0, stream>>>(Wk, Wr, Wx, Wh, Dw, Aw, w2);
        tkan_rec<true><<<dim3(BB), dim3(1024), 0, stream>>>(
            x, bias, stk, Db, Ab,
            (const void*)w2, (const void*)(w2 + 49152), (const void*)(w2 + 98304),
            (const void*)(w2 + 147456), (const void*)(w2 + 196608), (const void*)(w2 + 245760),
            outp);
    } else {
        tkan_rec<false><<<dim3(BB), dim3(1024), 0, stream>>>(
            x, bias, stk, Db, Ab,
            (const void*)Wk, (const void*)Wr, (const void*)Wx,
            (const void*)Wh, (const void*)Dw, (const void*)Aw,
            outp);
    }
}